// Round 5
// baseline (545.473 us; speedup 1.0000x reference)
//
#include <hip/hip_runtime.h>
#include <hip/hip_bf16.h>
#include <hip/hip_fp16.h>

#define N_NODES 50000
#define N_EDGES 800000
#define E_TOTAL (N_EDGES + N_NODES) /* 850000, self-loops appended */

typedef _Float16 f16x8 __attribute__((ext_vector_type(8)));
typedef _Float16 f16x4 __attribute__((ext_vector_type(4)));
typedef float f32x4 __attribute__((ext_vector_type(4)));

// ---------------------------------------------------------------------------
// CSR build: degree count -> exclusive scan -> scatter (by dst)
// ---------------------------------------------------------------------------
__global__ __launch_bounds__(256) void deg_kernel(const int* __restrict__ ei,
                                                  int* __restrict__ deg) {
  int e = blockIdx.x * 256 + threadIdx.x;
  if (e >= E_TOTAL) return;
  int d = (e < N_EDGES) ? ei[N_EDGES + e] : (e - N_EDGES);
  atomicAdd(&deg[d], 1);
}

__global__ __launch_bounds__(1024) void scan_kernel(const int* __restrict__ deg,
                                                    int* __restrict__ row_ptr) {
  __shared__ int sh[1024];
  __shared__ int carry_sh;
  const int t = threadIdx.x;
  if (t == 0) carry_sh = 0;
  __syncthreads();
  const int ITEMS = 8;
  for (int base = 0; base < N_NODES; base += 1024 * ITEMS) {
    int i0 = base + t * ITEMS;
    int v[ITEMS];
    int s = 0;
#pragma unroll
    for (int j = 0; j < ITEMS; j++) {
      v[j] = (i0 + j < N_NODES) ? deg[i0 + j] : 0;
      s += v[j];
    }
    sh[t] = s;
    __syncthreads();
    for (int off = 1; off < 1024; off <<= 1) {
      int tv = (t >= off) ? sh[t - off] : 0;
      __syncthreads();
      sh[t] += tv;
      __syncthreads();
    }
    int excl = sh[t] - s;
    int run = carry_sh + excl;
#pragma unroll
    for (int j = 0; j < ITEMS; j++) {
      if (i0 + j < N_NODES) row_ptr[i0 + j] = run;
      run += v[j];
    }
    int total = sh[1023];
    __syncthreads();
    if (t == 0) carry_sh += total;
    __syncthreads();
  }
  if (t == 0) row_ptr[N_NODES] = carry_sh;
}

__global__ __launch_bounds__(256) void scatter_kernel(const int* __restrict__ ei,
                                                      const int* __restrict__ row_ptr,
                                                      int* __restrict__ cursor,
                                                      int* __restrict__ csr_src) {
  int e = blockIdx.x * 256 + threadIdx.x;
  if (e >= E_TOTAL) return;
  int s, d;
  if (e < N_EDGES) {
    s = ei[e];
    d = ei[N_EDGES + e];
  } else {
    s = d = e - N_EDGES;
  }
  int pos = atomicAdd(&cursor[d], 1);
  csr_src[row_ptr[d] + pos] = s;
}

// ---------------------------------------------------------------------------
// W transpose: WT[n][k] = (f16) W[k][n], 256x256
// ---------------------------------------------------------------------------
__global__ __launch_bounds__(256) void transpose_w(const float* __restrict__ W,
                                                   _Float16* __restrict__ WT) {
  __shared__ float tile[32][33];
  const int bx = blockIdx.x * 32, by = blockIdx.y * 32;
  const int tx = threadIdx.x & 31, ty = threadIdx.x >> 5;
#pragma unroll
  for (int i = 0; i < 32; i += 8) tile[ty + i][tx] = W[(size_t)(by + ty + i) * 256 + bx + tx];
  __syncthreads();
#pragma unroll
  for (int i = 0; i < 32; i += 8)
    WT[(size_t)(bx + ty + i) * 256 + by + tx] = (_Float16)tile[tx][ty + i];
}

// ---------------------------------------------------------------------------
// MFMA f16 GEMM: C16[M,256] = A[M,256] * W, with WT[n][k] pre-transposed f16.
// 128x128 tile, 4 waves in 2x2, each wave 64x64 (4x4 frags of 16x16x32).
// LDS [128][40] f16 padded -> 2-way bank conflicts only (free).
// ---------------------------------------------------------------------------
template <bool A_IS_F16>
__global__ __launch_bounds__(256) void gemm_mfma(const void* __restrict__ Ap,
                                                 const _Float16* __restrict__ WT,
                                                 _Float16* __restrict__ C, int M) {
  __shared__ _Float16 As[128][40];
  __shared__ _Float16 Bs[128][40];
  const int t = threadIdx.x;
  const int lane = t & 63, w = t >> 6;
  const int wr = w & 1, wc = w >> 1;
  const int row0 = blockIdx.x * 128, col0 = blockIdx.y * 128;
  const int fr = lane & 15, fg = lane >> 4; // frag row/col and k-group

  f32x4 acc[4][4] = {};

  for (int k0 = 0; k0 < 256; k0 += 32) {
    // stage A (f32->f16 or f16 copy) and B (f16 copy from WT):
    // tile is 128 rows x 32 k = 512 f16x8 chunks, 2 per thread.
#pragma unroll
    for (int f = 0; f < 2; f++) {
      const int idx = f * 256 + t;
      const int sr = idx >> 2, sc = idx & 3;
      f16x8 va;
      if constexpr (A_IS_F16) {
        const _Float16* A = (const _Float16*)Ap;
        va = (row0 + sr < M) ? *(const f16x8*)(A + (size_t)(row0 + sr) * 256 + k0 + sc * 8)
                             : f16x8{};
      } else {
        const float* A = (const float*)Ap;
        va = f16x8{};
        if (row0 + sr < M) {
          float4 u0 = *(const float4*)(A + (size_t)(row0 + sr) * 256 + k0 + sc * 8);
          float4 u1 = *(const float4*)(A + (size_t)(row0 + sr) * 256 + k0 + sc * 8 + 4);
          va[0] = (_Float16)u0.x; va[1] = (_Float16)u0.y;
          va[2] = (_Float16)u0.z; va[3] = (_Float16)u0.w;
          va[4] = (_Float16)u1.x; va[5] = (_Float16)u1.y;
          va[6] = (_Float16)u1.z; va[7] = (_Float16)u1.w;
        }
      }
      f16x8 vb = *(const f16x8*)(WT + (size_t)(col0 + sr) * 256 + k0 + sc * 8);
      *(f16x8*)&As[sr][sc * 8] = va;
      *(f16x8*)&Bs[sr][sc * 8] = vb;
    }
    __syncthreads();

    f16x8 af[4], bf[4];
#pragma unroll
    for (int mi = 0; mi < 4; mi++) af[mi] = *(const f16x8*)&As[wr * 64 + mi * 16 + fr][fg * 8];
#pragma unroll
    for (int ni = 0; ni < 4; ni++) bf[ni] = *(const f16x8*)&Bs[wc * 64 + ni * 16 + fr][fg * 8];
#pragma unroll
    for (int mi = 0; mi < 4; mi++)
#pragma unroll
      for (int ni = 0; ni < 4; ni++)
        acc[mi][ni] = __builtin_amdgcn_mfma_f32_16x16x32_f16(af[mi], bf[ni], acc[mi][ni], 0, 0, 0);
    __syncthreads();
  }

  // epilogue: D col = lane&15, row = (lane>>4)*4 + reg  [m89 layout]
#pragma unroll
  for (int mi = 0; mi < 4; mi++) {
#pragma unroll
    for (int reg = 0; reg < 4; reg++) {
      int r = row0 + wr * 64 + mi * 16 + fg * 4 + reg;
      if (r < M) {
#pragma unroll
        for (int ni = 0; ni < 4; ni++) {
          int cc = col0 + wc * 64 + ni * 16 + fr;
          C[(size_t)r * 256 + cc] = (_Float16)acc[mi][ni][reg];
        }
      }
    }
  }
}

// ---------------------------------------------------------------------------
// attention coefficients: one wave per node, lane owns 4 channels
// ---------------------------------------------------------------------------
template <int H>
__global__ __launch_bounds__(256) void att_kernel(const _Float16* __restrict__ XH,
                                                  const float* __restrict__ att_s,
                                                  const float* __restrict__ att_d,
                                                  float* __restrict__ a_s,
                                                  float* __restrict__ a_d) {
  const int t = threadIdx.x;
  const int lane = t & 63, w = t >> 6;
  const int n = blockIdx.x * 4 + w;
  f16x4 raw = *(const f16x4*)(XH + (size_t)n * 256 + lane * 4);
  float4 ws = *(const float4*)&att_s[lane * 4];
  float4 wd = *(const float4*)&att_d[lane * 4];
  float f0 = (float)raw[0], f1 = (float)raw[1], f2 = (float)raw[2], f3 = (float)raw[3];
  float vs = f0 * ws.x + f1 * ws.y + f2 * ws.z + f3 * ws.w;
  float vd = f0 * wd.x + f1 * wd.y + f2 * wd.z + f3 * wd.w;
  if constexpr (H == 4) {
#pragma unroll
    for (int off = 1; off < 16; off <<= 1) {
      vs += __shfl_xor(vs, off, 64);
      vd += __shfl_xor(vd, off, 64);
    }
    if ((lane & 15) == 0) {
      a_s[(size_t)n * 4 + (lane >> 4)] = vs;
      a_d[(size_t)n * 4 + (lane >> 4)] = vd;
    }
  } else {
#pragma unroll
    for (int off = 1; off < 64; off <<= 1) {
      vs += __shfl_xor(vs, off, 64);
      vd += __shfl_xor(vd, off, 64);
    }
    if (lane == 0) {
      a_s[n] = vs;
      a_d[n] = vd;
    }
  }
}

// ---------------------------------------------------------------------------
// ONLINE segment softmax + weighted gather: one wave per node, single pass.
// Flash-style running (m, sum, acc) with always-multiply rescale.
// Chunk of CH edges; next chunk's csr_src + a_s prefetched before the
// current chunk's row gathers (T14 issue-early), so the alpha chain
// overlaps the 16/64 in-flight row loads.
// H=4: CH=16, lane&15 = edge slot, lane>>4 = head (owns its channels).
// H=1: CH=64, lane = edge slot.
// ---------------------------------------------------------------------------
template <int H, bool ELU_OUT, bool OUT_F16>
__global__ __launch_bounds__(256) void aggregate_kernel(
    const _Float16* __restrict__ XH16, const float* __restrict__ a_s,
    const float* __restrict__ a_d, const int* __restrict__ row_ptr,
    const int* __restrict__ csr_src, const float* __restrict__ bias,
    void* __restrict__ outp) {
  constexpr int CH = (H == 4) ? 16 : 64;
  const int t = threadIdx.x;
  const int lane = t & 63, w = t >> 6;
  const int d = blockIdx.x * 4 + w;
  const int e0 = row_ptr[d];
  const int deg = row_ptr[d + 1] - e0;
  const int li = (H == 4) ? (lane & 15) : lane;
  const int h4 = (H == 4) ? (lane >> 4) : 0;
  const float adv = (H == 4) ? a_d[(size_t)d * 4 + h4] : a_d[d];

  float m_run = -1e30f;
  float dnp = 0.f; // per-lane partial of running denom (scaled like acc)
  float acc0 = 0.f, acc1 = 0.f, acc2 = 0.f, acc3 = 0.f;

  // prefetch chunk 0: src index + its random a_s value
  int s_cur = 0;
  float as_cur = -1e30f;
  if (li < deg) {
    s_cur = csr_src[e0 + li];
    as_cur = (H == 4) ? a_s[(size_t)s_cur * 4 + h4] : a_s[s_cur];
  }

  for (int base = 0; base < deg; base += CH) {
    const int cnt = min(CH, deg - base);
    // prefetch next chunk (loads issue now, consumed next iteration)
    const int nb = base + CH;
    int s_nx = 0;
    float as_nx = -1e30f;
    if (nb + li < deg) {
      s_nx = csr_src[e0 + nb + li];
      as_nx = (H == 4) ? a_s[(size_t)s_nx * 4 + h4] : a_s[s_nx];
    }

    // e with LeakyReLU; invalid slots carry -1e30 -> leaky -> -2e29: max-
    // neutral and exp() underflows to exactly 0.
    float e = (li < cnt) ? (as_cur + adv) : -1e30f;
    e = e > 0.f ? e : 0.2f * e;

    // chunk max (within head group), combine with running max, rescale
    float cm = e;
#pragma unroll
    for (int off = 1; off < CH; off <<= 1) cm = fmaxf(cm, __shfl_xor(cm, off, 64));
    float m_new = fmaxf(m_run, cm);
    float sc = __expf(m_run - m_new); // ==1 when max unchanged; 0 on first chunk
    acc0 *= sc; acc1 *= sc; acc2 *= sc; acc3 *= sc;
    dnp *= sc;
    m_run = m_new;

    float p = __expf(e - m_run); // unnormalized alpha; 0 for invalid slots
    dnp += p;

    // gather: broadcast (src, p) from slot j, whole wave reads the f16 row
#define GAT_BODY(j)                                                           \
  {                                                                           \
    int sj = __builtin_amdgcn_readfirstlane(__shfl(s_cur, (j), 64));          \
    float alj = (H == 4) ? __shfl(p, (lane & 48) + (j), 64)                   \
                         : __shfl(p, (j), 64);                                \
    f16x4 raw = *(const f16x4*)(XH16 + (size_t)sj * 256 + lane * 4);          \
    acc0 = fmaf(alj, (float)raw[0], acc0);                                    \
    acc1 = fmaf(alj, (float)raw[1], acc1);                                    \
    acc2 = fmaf(alj, (float)raw[2], acc2);                                    \
    acc3 = fmaf(alj, (float)raw[3], acc3);                                    \
  }
    if (cnt == CH) {
#pragma unroll
      for (int j = 0; j < CH; j++) GAT_BODY(j)
    } else {
      for (int j = 0; j < cnt; j++) GAT_BODY(j)
    }
#undef GAT_BODY
    s_cur = s_nx;
    as_cur = as_nx;
  }

  // total denom over the head group
#pragma unroll
  for (int off = 1; off < CH; off <<= 1) dnp += __shfl_xor(dnp, off, 64);
  const float inv = 1.f / (dnp + 1e-16f);

  float4 bv = *(const float4*)&bias[lane * 4];
  float v0 = fmaf(acc0, inv, bv.x), v1 = fmaf(acc1, inv, bv.y);
  float v2 = fmaf(acc2, inv, bv.z), v3 = fmaf(acc3, inv, bv.w);
  if constexpr (ELU_OUT) {
    v0 = v0 > 0.f ? v0 : (__expf(v0) - 1.f);
    v1 = v1 > 0.f ? v1 : (__expf(v1) - 1.f);
    v2 = v2 > 0.f ? v2 : (__expf(v2) - 1.f);
    v3 = v3 > 0.f ? v3 : (__expf(v3) - 1.f);
  }
  if constexpr (OUT_F16) {
    _Float16* out = (_Float16*)outp;
    f16x4 ov;
    ov[0] = (_Float16)v0; ov[1] = (_Float16)v1;
    ov[2] = (_Float16)v2; ov[3] = (_Float16)v3;
    *(f16x4*)(out + (size_t)d * 256 + lane * 4) = ov;
  } else {
    float* out = (float*)outp;
    *(float4*)(out + (size_t)d * 256 + lane * 4) = make_float4(v0, v1, v2, v3);
  }
}

// ---------------------------------------------------------------------------
extern "C" void kernel_launch(void* const* d_in, const int* in_sizes, int n_in,
                              void* d_out, int out_size, void* d_ws, size_t ws_size,
                              hipStream_t stream) {
  const float* x = (const float*)d_in[0];
  const int* ei = (const int*)d_in[1];
  const float* W0 = (const float*)d_in[2];
  const float* as0 = (const float*)d_in[3];
  const float* ad0 = (const float*)d_in[4];
  const float* b0 = (const float*)d_in[5];
  const float* W1 = (const float*)d_in[6];
  const float* as1 = (const float*)d_in[7];
  const float* ad1 = (const float*)d_in[8];
  const float* b1 = (const float*)d_in[9];
  const float* W2 = (const float*)d_in[10];
  const float* as2 = (const float*)d_in[11];
  const float* ad2 = (const float*)d_in[12];
  const float* b2 = (const float*)d_in[13];
  float* out = (float*)d_out;

  char* p = (char*)d_ws;
  _Float16* XH16 = (_Float16*)p;
  p += (size_t)N_NODES * 256 * 2; // 25.6 MB: GEMM out / gather table
  _Float16* H16 = (_Float16*)p;
  p += (size_t)N_NODES * 256 * 2; // 25.6 MB: aggregate out -> next GEMM in
  _Float16* WT = (_Float16*)p;
  p += 256 * 256 * 2; // 128 KB transposed weights
  float* a_s = (float*)p;
  p += (size_t)N_NODES * 4 * 4;
  float* a_d = (float*)p;
  p += (size_t)N_NODES * 4 * 4;
  int* row_ptr = (int*)p;
  p += 200064;
  int* deg = (int*)p;
  p += (size_t)N_NODES * 4;
  int* cursor = (int*)p;
  p += (size_t)N_NODES * 4;
  int* csr_src = (int*)p;
  p += (size_t)E_TOTAL * 4;

  hipMemsetAsync(deg, 0, (size_t)N_NODES * 4, stream);
  hipMemsetAsync(cursor, 0, (size_t)N_NODES * 4, stream);
  deg_kernel<<<(E_TOTAL + 255) / 256, 256, 0, stream>>>(ei, deg);
  scan_kernel<<<1, 1024, 0, stream>>>(deg, row_ptr);
  scatter_kernel<<<(E_TOTAL + 255) / 256, 256, 0, stream>>>(ei, row_ptr, cursor, csr_src);

  dim3 tgrid(8, 8);
  dim3 ggrid((N_NODES + 127) / 128, 2);
  const int ngrid = N_NODES / 4; // 12500, exact

  // layer 0: 4 heads x 64, concat, ELU
  transpose_w<<<tgrid, 256, 0, stream>>>(W0, WT);
  gemm_mfma<false><<<ggrid, 256, 0, stream>>>(x, WT, XH16, N_NODES);
  att_kernel<4><<<ngrid, 256, 0, stream>>>(XH16, as0, ad0, a_s, a_d);
  aggregate_kernel<4, true, true><<<ngrid, 256, 0, stream>>>(XH16, a_s, a_d, row_ptr, csr_src, b0, H16);
  // layer 1
  transpose_w<<<tgrid, 256, 0, stream>>>(W1, WT);
  gemm_mfma<true><<<ggrid, 256, 0, stream>>>(H16, WT, XH16, N_NODES);
  att_kernel<4><<<ngrid, 256, 0, stream>>>(XH16, as1, ad1, a_s, a_d);
  aggregate_kernel<4, true, true><<<ngrid, 256, 0, stream>>>(XH16, a_s, a_d, row_ptr, csr_src, b1, H16);
  // layer 2: 1 head x 256, mean over 1 head = identity, no ELU, f32 out
  transpose_w<<<tgrid, 256, 0, stream>>>(W2, WT);
  gemm_mfma<true><<<ggrid, 256, 0, stream>>>(H16, WT, XH16, N_NODES);
  att_kernel<1><<<ngrid, 256, 0, stream>>>(XH16, as2, ad2, a_s, a_d);
  aggregate_kernel<1, false, false><<<ngrid, 256, 0, stream>>>(XH16, a_s, a_d, row_ptr, csr_src, b2, out);
}

// Round 6
// 489.654 us; speedup vs baseline: 1.1140x; 1.1140x over previous
//
#include <hip/hip_runtime.h>
#include <hip/hip_bf16.h>
#include <hip/hip_fp16.h>

#define N_NODES 50000
#define N_EDGES 800000
#define E_TOTAL (N_EDGES + N_NODES) /* 850000, self-loops appended */

typedef _Float16 f16x8 __attribute__((ext_vector_type(8)));
typedef _Float16 f16x4 __attribute__((ext_vector_type(4)));
typedef float f32x4 __attribute__((ext_vector_type(4)));

// ---------------------------------------------------------------------------
// CSR build: degree count -> exclusive scan -> scatter (by dst)
// ---------------------------------------------------------------------------
__global__ __launch_bounds__(256) void deg_kernel(const int* __restrict__ ei,
                                                  int* __restrict__ deg) {
  int e = blockIdx.x * 256 + threadIdx.x;
  if (e >= E_TOTAL) return;
  int d = (e < N_EDGES) ? ei[N_EDGES + e] : (e - N_EDGES);
  atomicAdd(&deg[d], 1);
}

// wave-shfl scan: 4 barriers per 8192-element block instead of ~20
__global__ __launch_bounds__(1024) void scan_kernel(const int* __restrict__ deg,
                                                    int* __restrict__ row_ptr) {
  __shared__ int wsum[16];
  __shared__ int carry_sh;
  const int t = threadIdx.x, lane = t & 63, wv = t >> 6;
  if (t == 0) carry_sh = 0;
  __syncthreads();
  const int ITEMS = 8;
  for (int base = 0; base < N_NODES; base += 1024 * ITEMS) {
    int i0 = base + t * ITEMS;
    int v[ITEMS];
    int s = 0;
#pragma unroll
    for (int j = 0; j < ITEMS; j++) {
      v[j] = (i0 + j < N_NODES) ? deg[i0 + j] : 0;
      s += v[j];
    }
    // wave inclusive scan of s
    int sc = s;
#pragma unroll
    for (int off = 1; off < 64; off <<= 1) {
      int u = __shfl_up(sc, off, 64);
      if (lane >= off) sc += u;
    }
    if (lane == 63) wsum[wv] = sc;
    __syncthreads();
    if (wv == 0 && lane < 16) {
      int ws = wsum[lane];
#pragma unroll
      for (int off = 1; off < 16; off <<= 1) {
        int u = __shfl_up(ws, off, 64);
        if (lane >= off) ws += u;
      }
      wsum[lane] = ws;
    }
    __syncthreads();
    int wbase = carry_sh + (wv ? wsum[wv - 1] : 0);
    int run = wbase + sc - s; // exclusive prefix for this thread
#pragma unroll
    for (int j = 0; j < ITEMS; j++) {
      if (i0 + j < N_NODES) row_ptr[i0 + j] = run;
      run += v[j];
    }
    __syncthreads(); // all reads of carry_sh/wsum done
    if (t == 0) carry_sh += wsum[15];
    __syncthreads();
  }
  if (t == 0) row_ptr[N_NODES] = carry_sh;
}

__global__ __launch_bounds__(256) void scatter_kernel(const int* __restrict__ ei,
                                                      const int* __restrict__ row_ptr,
                                                      int* __restrict__ cursor,
                                                      int* __restrict__ csr_src,
                                                      int* __restrict__ csr_pos) {
  int e = blockIdx.x * 256 + threadIdx.x;
  if (e >= E_TOTAL) return;
  int s, d;
  if (e < N_EDGES) {
    s = ei[e];
    d = ei[N_EDGES + e];
  } else {
    s = d = e - N_EDGES;
  }
  int pos = row_ptr[d] + atomicAdd(&cursor[d], 1);
  csr_src[pos] = s;
  csr_pos[e] = pos;
}

// ---------------------------------------------------------------------------
// edge-parallel e = LeakyReLU(a_s[src] + a_d[dst]) written in CSR order.
// a_s/a_d tables are 800KB -> L2-resident; TLP hides the random-read latency.
// ---------------------------------------------------------------------------
template <int H>
__global__ __launch_bounds__(256) void edge_e_kernel(const int* __restrict__ ei,
                                                     const int* __restrict__ csr_pos,
                                                     const float* __restrict__ a_s,
                                                     const float* __restrict__ a_d,
                                                     float* __restrict__ e_csr) {
  int e = blockIdx.x * 256 + threadIdx.x;
  if (e >= E_TOTAL) return;
  int s, d;
  if (e < N_EDGES) {
    s = ei[e];
    d = ei[N_EDGES + e];
  } else {
    s = d = e - N_EDGES;
  }
  int pos = csr_pos[e];
  if constexpr (H == 4) {
    float4 as4 = *(const float4*)&a_s[(size_t)s * 4];
    float4 ad4 = *(const float4*)&a_d[(size_t)d * 4];
    float4 ev;
    ev.x = as4.x + ad4.x; ev.x = ev.x > 0.f ? ev.x : 0.2f * ev.x;
    ev.y = as4.y + ad4.y; ev.y = ev.y > 0.f ? ev.y : 0.2f * ev.y;
    ev.z = as4.z + ad4.z; ev.z = ev.z > 0.f ? ev.z : 0.2f * ev.z;
    ev.w = as4.w + ad4.w; ev.w = ev.w > 0.f ? ev.w : 0.2f * ev.w;
    *(float4*)&e_csr[(size_t)pos * 4] = ev;
  } else {
    float ev = a_s[s] + a_d[d];
    ev = ev > 0.f ? ev : 0.2f * ev;
    e_csr[pos] = ev;
  }
}

// ---------------------------------------------------------------------------
// W transpose: WT[n][k] = (f16) W[k][n], 256x256
// ---------------------------------------------------------------------------
__global__ __launch_bounds__(256) void transpose_w(const float* __restrict__ W,
                                                   _Float16* __restrict__ WT) {
  __shared__ float tile[32][33];
  const int bx = blockIdx.x * 32, by = blockIdx.y * 32;
  const int tx = threadIdx.x & 31, ty = threadIdx.x >> 5;
#pragma unroll
  for (int i = 0; i < 32; i += 8) tile[ty + i][tx] = W[(size_t)(by + ty + i) * 256 + bx + tx];
  __syncthreads();
#pragma unroll
  for (int i = 0; i < 32; i += 8)
    WT[(size_t)(bx + ty + i) * 256 + by + tx] = (_Float16)tile[tx][ty + i];
}

// ---------------------------------------------------------------------------
// MFMA f16 GEMM: C16[M,256] = A[M,256] * W, with WT[n][k] pre-transposed f16.
// 128x128 tile, 4 waves in 2x2, each wave 64x64 (4x4 frags of 16x16x32).
// LDS [128][40] f16 padded -> 2-way bank conflicts only (free).
// ---------------------------------------------------------------------------
template <bool A_IS_F16>
__global__ __launch_bounds__(256) void gemm_mfma(const void* __restrict__ Ap,
                                                 const _Float16* __restrict__ WT,
                                                 _Float16* __restrict__ C, int M) {
  __shared__ _Float16 As[128][40];
  __shared__ _Float16 Bs[128][40];
  const int t = threadIdx.x;
  const int lane = t & 63, w = t >> 6;
  const int wr = w & 1, wc = w >> 1;
  const int row0 = blockIdx.x * 128, col0 = blockIdx.y * 128;
  const int fr = lane & 15, fg = lane >> 4; // frag row/col and k-group

  f32x4 acc[4][4] = {};

  for (int k0 = 0; k0 < 256; k0 += 32) {
#pragma unroll
    for (int f = 0; f < 2; f++) {
      const int idx = f * 256 + t;
      const int sr = idx >> 2, sc = idx & 3;
      f16x8 va;
      if constexpr (A_IS_F16) {
        const _Float16* A = (const _Float16*)Ap;
        va = (row0 + sr < M) ? *(const f16x8*)(A + (size_t)(row0 + sr) * 256 + k0 + sc * 8)
                             : f16x8{};
      } else {
        const float* A = (const float*)Ap;
        va = f16x8{};
        if (row0 + sr < M) {
          float4 u0 = *(const float4*)(A + (size_t)(row0 + sr) * 256 + k0 + sc * 8);
          float4 u1 = *(const float4*)(A + (size_t)(row0 + sr) * 256 + k0 + sc * 8 + 4);
          va[0] = (_Float16)u0.x; va[1] = (_Float16)u0.y;
          va[2] = (_Float16)u0.z; va[3] = (_Float16)u0.w;
          va[4] = (_Float16)u1.x; va[5] = (_Float16)u1.y;
          va[6] = (_Float16)u1.z; va[7] = (_Float16)u1.w;
        }
      }
      f16x8 vb = *(const f16x8*)(WT + (size_t)(col0 + sr) * 256 + k0 + sc * 8);
      *(f16x8*)&As[sr][sc * 8] = va;
      *(f16x8*)&Bs[sr][sc * 8] = vb;
    }
    __syncthreads();

    f16x8 af[4], bf[4];
#pragma unroll
    for (int mi = 0; mi < 4; mi++) af[mi] = *(const f16x8*)&As[wr * 64 + mi * 16 + fr][fg * 8];
#pragma unroll
    for (int ni = 0; ni < 4; ni++) bf[ni] = *(const f16x8*)&Bs[wc * 64 + ni * 16 + fr][fg * 8];
#pragma unroll
    for (int mi = 0; mi < 4; mi++)
#pragma unroll
      for (int ni = 0; ni < 4; ni++)
        acc[mi][ni] = __builtin_amdgcn_mfma_f32_16x16x32_f16(af[mi], bf[ni], acc[mi][ni], 0, 0, 0);
    __syncthreads();
  }

  // epilogue: D col = lane&15, row = (lane>>4)*4 + reg  [m89 layout]
#pragma unroll
  for (int mi = 0; mi < 4; mi++) {
#pragma unroll
    for (int reg = 0; reg < 4; reg++) {
      int r = row0 + wr * 64 + mi * 16 + fg * 4 + reg;
      if (r < M) {
#pragma unroll
        for (int ni = 0; ni < 4; ni++) {
          int cc = col0 + wc * 64 + ni * 16 + fr;
          C[(size_t)r * 256 + cc] = (_Float16)acc[mi][ni][reg];
        }
      }
    }
  }
}

// ---------------------------------------------------------------------------
// attention coefficients: one wave per node, lane owns 4 channels
// ---------------------------------------------------------------------------
template <int H>
__global__ __launch_bounds__(256) void att_kernel(const _Float16* __restrict__ XH,
                                                  const float* __restrict__ att_s,
                                                  const float* __restrict__ att_d,
                                                  float* __restrict__ a_s,
                                                  float* __restrict__ a_d) {
  const int t = threadIdx.x;
  const int lane = t & 63, w = t >> 6;
  const int n = blockIdx.x * 4 + w;
  f16x4 raw = *(const f16x4*)(XH + (size_t)n * 256 + lane * 4);
  float4 ws = *(const float4*)&att_s[lane * 4];
  float4 wd = *(const float4*)&att_d[lane * 4];
  float f0 = (float)raw[0], f1 = (float)raw[1], f2 = (float)raw[2], f3 = (float)raw[3];
  float vs = f0 * ws.x + f1 * ws.y + f2 * ws.z + f3 * ws.w;
  float vd = f0 * wd.x + f1 * wd.y + f2 * wd.z + f3 * wd.w;
  if constexpr (H == 4) {
#pragma unroll
    for (int off = 1; off < 16; off <<= 1) {
      vs += __shfl_xor(vs, off, 64);
      vd += __shfl_xor(vd, off, 64);
    }
    if ((lane & 15) == 0) {
      a_s[(size_t)n * 4 + (lane >> 4)] = vs;
      a_d[(size_t)n * 4 + (lane >> 4)] = vd;
    }
  } else {
#pragma unroll
    for (int off = 1; off < 64; off <<= 1) {
      vs += __shfl_xor(vs, off, 64);
      vd += __shfl_xor(vd, off, 64);
    }
    if (lane == 0) {
      a_s[n] = vs;
      a_d[n] = vd;
    }
  }
}

// ---------------------------------------------------------------------------
// segment softmax + weighted gather, e values precomputed in CSR order:
// pass 1: coalesced max; pass 2: coalesced exp + broadcast row-gather.
// One wave per node; lane&15 = edge slot, lane>>4 = head (H=4) / dup (H=1).
// ---------------------------------------------------------------------------
template <int H, bool ELU_OUT, bool OUT_F16>
__global__ __launch_bounds__(256) void aggregate_kernel(
    const _Float16* __restrict__ XH16, const float* __restrict__ e_csr,
    const int* __restrict__ row_ptr, const int* __restrict__ csr_src,
    const float* __restrict__ bias, void* __restrict__ outp) {
  const int t = threadIdx.x;
  const int lane = t & 63, w = t >> 6;
  const int d = blockIdx.x * 4 + w;
  const int e0 = row_ptr[d];
  const int deg = row_ptr[d + 1] - e0;
  const int li = lane & 15;
  const int h4 = (H == 4) ? (lane >> 4) : 0;

  // pass 1: segment max (coalesced e_csr reads only)
  float m = -1e30f;
  for (int i = li; i < deg; i += 16) {
    float e = (H == 4) ? e_csr[(size_t)(e0 + i) * 4 + h4] : e_csr[e0 + i];
    m = fmaxf(m, e);
  }
#pragma unroll
  for (int off = 1; off < 16; off <<= 1) m = fmaxf(m, __shfl_xor(m, off, 64));

  // pass 2: exp + gather in chunks of 16 edges
  float dnp = 0.f;
  float acc0 = 0.f, acc1 = 0.f, acc2 = 0.f, acc3 = 0.f;
  for (int base = 0; base < deg; base += 16) {
    const int cnt = min(16, deg - base);
    int s_cur = 0;
    float p = 0.f;
    if (li < cnt) {
      s_cur = csr_src[e0 + base + li];
      float e = (H == 4) ? e_csr[(size_t)(e0 + base + li) * 4 + h4] : e_csr[e0 + base + li];
      p = __expf(e - m);
    }
    dnp += p;
#define GAT_BODY(j)                                                           \
  {                                                                           \
    int sj = __builtin_amdgcn_readfirstlane(__shfl(s_cur, (j), 64));          \
    float alj = __shfl(p, (lane & 48) + (j), 64);                             \
    f16x4 raw = *(const f16x4*)(XH16 + (size_t)sj * 256 + lane * 4);          \
    acc0 = fmaf(alj, (float)raw[0], acc0);                                    \
    acc1 = fmaf(alj, (float)raw[1], acc1);                                    \
    acc2 = fmaf(alj, (float)raw[2], acc2);                                    \
    acc3 = fmaf(alj, (float)raw[3], acc3);                                    \
  }
    if (cnt == 16) {
#pragma unroll
      for (int j = 0; j < 16; j++) GAT_BODY(j)
    } else {
      for (int j = 0; j < cnt; j++) GAT_BODY(j)
    }
#undef GAT_BODY
  }
  // denom: sum the 16 slot-partials within each 16-lane group
#pragma unroll
  for (int off = 1; off < 16; off <<= 1) dnp += __shfl_xor(dnp, off, 64);
  const float inv = 1.f / (dnp + 1e-16f);

  float4 bv = *(const float4*)&bias[lane * 4];
  float v0 = fmaf(acc0, inv, bv.x), v1 = fmaf(acc1, inv, bv.y);
  float v2 = fmaf(acc2, inv, bv.z), v3 = fmaf(acc3, inv, bv.w);
  if constexpr (ELU_OUT) {
    v0 = v0 > 0.f ? v0 : (__expf(v0) - 1.f);
    v1 = v1 > 0.f ? v1 : (__expf(v1) - 1.f);
    v2 = v2 > 0.f ? v2 : (__expf(v2) - 1.f);
    v3 = v3 > 0.f ? v3 : (__expf(v3) - 1.f);
  }
  if constexpr (OUT_F16) {
    _Float16* out = (_Float16*)outp;
    f16x4 ov;
    ov[0] = (_Float16)v0; ov[1] = (_Float16)v1;
    ov[2] = (_Float16)v2; ov[3] = (_Float16)v3;
    *(f16x4*)(out + (size_t)d * 256 + lane * 4) = ov;
  } else {
    float* out = (float*)outp;
    *(float4*)(out + (size_t)d * 256 + lane * 4) = make_float4(v0, v1, v2, v3);
  }
}

// ---------------------------------------------------------------------------
extern "C" void kernel_launch(void* const* d_in, const int* in_sizes, int n_in,
                              void* d_out, int out_size, void* d_ws, size_t ws_size,
                              hipStream_t stream) {
  const float* x = (const float*)d_in[0];
  const int* ei = (const int*)d_in[1];
  const float* W0 = (const float*)d_in[2];
  const float* as0 = (const float*)d_in[3];
  const float* ad0 = (const float*)d_in[4];
  const float* b0 = (const float*)d_in[5];
  const float* W1 = (const float*)d_in[6];
  const float* as1 = (const float*)d_in[7];
  const float* ad1 = (const float*)d_in[8];
  const float* b1 = (const float*)d_in[9];
  const float* W2 = (const float*)d_in[10];
  const float* as2 = (const float*)d_in[11];
  const float* ad2 = (const float*)d_in[12];
  const float* b2 = (const float*)d_in[13];
  float* out = (float*)d_out;

  char* p = (char*)d_ws;
  _Float16* XH16 = (_Float16*)p;
  p += (size_t)N_NODES * 256 * 2; // 25.6 MB: GEMM out / gather table
  _Float16* H16 = (_Float16*)p;
  p += (size_t)N_NODES * 256 * 2; // 25.6 MB: aggregate out -> next GEMM in
  _Float16* WT = (_Float16*)p;
  p += 256 * 256 * 2; // 128 KB transposed weights
  float* a_s = (float*)p;
  p += (size_t)N_NODES * 4 * 4;
  float* a_d = (float*)p;
  p += (size_t)N_NODES * 4 * 4;
  int* row_ptr = (int*)p;
  p += 200064;
  int* deg = (int*)p;
  p += (size_t)N_NODES * 4;
  int* cursor = (int*)p;
  p += (size_t)N_NODES * 4;
  int* csr_src = (int*)p;
  p += (size_t)E_TOTAL * 4;
  int* csr_pos = (int*)p;
  p += (size_t)E_TOTAL * 4; // 3.4 MB
  float* e_csr = (float*)p;
  p += (size_t)E_TOTAL * 4 * 4; // 13.6 MB (H=4 planes interleaved)

  hipMemsetAsync(deg, 0, (size_t)N_NODES * 4, stream);
  hipMemsetAsync(cursor, 0, (size_t)N_NODES * 4, stream);
  deg_kernel<<<(E_TOTAL + 255) / 256, 256, 0, stream>>>(ei, deg);
  scan_kernel<<<1, 1024, 0, stream>>>(deg, row_ptr);
  scatter_kernel<<<(E_TOTAL + 255) / 256, 256, 0, stream>>>(ei, row_ptr, cursor, csr_src, csr_pos);

  dim3 tgrid(8, 8);
  dim3 ggrid((N_NODES + 127) / 128, 2);
  const int ngrid = N_NODES / 4;              // 12500, exact
  const int egrid = (E_TOTAL + 255) / 256;

  // layer 0: 4 heads x 64, concat, ELU
  transpose_w<<<tgrid, 256, 0, stream>>>(W0, WT);
  gemm_mfma<false><<<ggrid, 256, 0, stream>>>(x, WT, XH16, N_NODES);
  att_kernel<4><<<ngrid, 256, 0, stream>>>(XH16, as0, ad0, a_s, a_d);
  edge_e_kernel<4><<<egrid, 256, 0, stream>>>(ei, csr_pos, a_s, a_d, e_csr);
  aggregate_kernel<4, true, true><<<ngrid, 256, 0, stream>>>(XH16, e_csr, row_ptr, csr_src, b0, H16);
  // layer 1
  transpose_w<<<tgrid, 256, 0, stream>>>(W1, WT);
  gemm_mfma<true><<<ggrid, 256, 0, stream>>>(H16, WT, XH16, N_NODES);
  att_kernel<4><<<ngrid, 256, 0, stream>>>(XH16, as1, ad1, a_s, a_d);
  edge_e_kernel<4><<<egrid, 256, 0, stream>>>(ei, csr_pos, a_s, a_d, e_csr);
  aggregate_kernel<4, true, true><<<ngrid, 256, 0, stream>>>(XH16, e_csr, row_ptr, csr_src, b1, H16);
  // layer 2: 1 head x 256, mean over 1 head = identity, no ELU, f32 out
  transpose_w<<<tgrid, 256, 0, stream>>>(W2, WT);
  gemm_mfma<true><<<ggrid, 256, 0, stream>>>(H16, WT, XH16, N_NODES);
  att_kernel<1><<<ngrid, 256, 0, stream>>>(XH16, as2, ad2, a_s, a_d);
  edge_e_kernel<1><<<egrid, 256, 0, stream>>>(ei, csr_pos, a_s, a_d, e_csr);
  aggregate_kernel<1, false, false><<<ngrid, 256, 0, stream>>>(XH16, e_csr, row_ptr, csr_src, b2, out);
}